// Round 1
// baseline (7708.355 us; speedup 1.0000x reference)
//
#include <hip/hip_runtime.h>

#define Bsz 256
#define Tt  512
#define Hd  1024
#define Cc  10
#define RG  32     // rows per group
#define NH  32     // h-cols per block
#define THREADS 512

typedef short bf16x8 __attribute__((ext_vector_type(8)));
typedef float f32x4 __attribute__((ext_vector_type(4)));
typedef unsigned u32x4 __attribute__((ext_vector_type(4)));

__device__ __forceinline__ unsigned short f2bf(float f) {
  unsigned u = __builtin_bit_cast(unsigned, f);
  u = (u + 0x7FFFu + ((u >> 16) & 1u)) >> 16;   // RTNE
  return (unsigned short)u;
}
__device__ __forceinline__ float bf2f(unsigned short s) {
  unsigned u = ((unsigned)s) << 16;
  return __builtin_bit_cast(float, u);
}
__device__ __forceinline__ float sigmf_(float z) { return 1.0f / (1.0f + __expf(-z)); }
__device__ __forceinline__ float tanhf_(float z) { return 1.0f - 2.0f / (__expf(2.0f * z) + 1.0f); }

__launch_bounds__(THREADS, 2)
__global__ void lstm_kernel(
    const float* __restrict__ x,
    const float* __restrict__ wgx, const float* __restrict__ wgh, const float* __restrict__ bg,
    const float* __restrict__ wix, const float* __restrict__ wih, const float* __restrict__ bi,
    const float* __restrict__ wfx, const float* __restrict__ wfh, const float* __restrict__ bfp,
    const float* __restrict__ wox, const float* __restrict__ woh, const float* __restrict__ bo,
    const float* __restrict__ wph, const float* __restrict__ bp,
    float* __restrict__ out,
    unsigned short* __restrict__ hbuf,   // [256][1024] bf16 in d_ws
    unsigned* __restrict__ flags)        // [256] group barrier flags in d_ws
{
  extern __shared__ char smem[];
  char*  hls  = smem;                               // [32 rows][2048B] swizzled bf16, 64KB
  float* zbuf = (float*)(smem + 65536);             // [32][128] f32, 16KB
  float* xbuf = (float*)(smem + 65536 + 16384);     // [32]
  float* wxb  = xbuf + 32;                          // [4][32]
  float* bbl  = wxb + 128;                          // [4][32]

  const int tid = threadIdx.x;
  const int l   = tid & 63;
  const int w   = tid >> 6;          // wave 0..7
  const int g   = blockIdx.x >> 5;   // group 0..7
  const int j   = blockIdx.x & 31;   // col block 0..31
  const int r0  = g * RG;
  const int hc0 = j * NH;

  // ---- init: zero LDS h (h_0 = 0) ----
  {
    u32x4 z4 = {0u,0u,0u,0u};
    #pragma unroll
    for (int i = 0; i < 8; ++i) {
      int m = tid + i * THREADS;
      *(u32x4*)(hls + m * 16) = z4;
    }
  }
  // ---- wx, b slices into LDS ----
  if (tid < 128) {
    int q = tid >> 5, hcl = tid & 31;
    const float* px = (q == 0) ? wgx : (q == 1) ? wix : (q == 2) ? wfx : wox;
    const float* pb = (q == 0) ? bg  : (q == 1) ? bi  : (q == 2) ? bfp : bo;
    wxb[tid] = px[hc0 + hcl];
    bbl[tid] = pb[hc0 + hcl];
  }

  // ---- Wh slice -> register B-fragments (loaded ONCE, reused 512 steps) ----
  // wave w -> z-cols [w*16, w*16+16): gate q = w>>1, h-col = hc0 + (w&1)*16 + (l&15)
  const int q = w >> 1;
  const float* whp = (q == 0) ? wgh : (q == 1) ? wih : (q == 2) ? wfh : woh;
  const int bcol = hc0 + ((w & 1) << 4) + (l & 15);
  const int kb = ((l >> 4) & 3) * 8;     // k sub-chunk base within 32
  bf16x8 bq[32];
  #pragma unroll
  for (int kc = 0; kc < 32; ++kc) {
    bf16x8 v;
    #pragma unroll
    for (int e = 0; e < 8; ++e) {
      v[e] = (short)f2bf(whp[(kc * 32 + kb + e) * Hd + bcol]);
    }
    bq[kc] = v;
  }

  __syncthreads();

  // per-thread c-state: idx = tid + e*512 over [0,1024) = (r = idx>>5, hc = idx&31)
  float creg0 = 0.f, creg1 = 0.f;

  const int roff0 = (l & 15) * 2048;        // A-frag row (tile 0)
  const int roff1 = roff0 + 16 * 2048;      // A-frag row (tile 1)
  const int swz   = (l & 7) << 4;           // LDS XOR swizzle (matches stage-write)
  const int kboff = ((l >> 4) & 3) * 16;    // byte offset of k sub-chunk

  unsigned* myflags = flags + (g << 5);

  #pragma unroll 1
  for (int t = 0; t < Tt; ++t) {
    if (tid < 32) xbuf[tid] = x[(r0 + tid) * Tt + t];

    // ---- z = h @ Wh : A from LDS (swizzled), B from registers ----
    f32x4 acc0 = {0.f,0.f,0.f,0.f};
    f32x4 acc1 = {0.f,0.f,0.f,0.f};
    #pragma unroll
    for (int kc = 0; kc < 32; ++kc) {
      int boff = (kc * 64 + kboff) ^ swz;
      bf16x8 a0 = *(const bf16x8*)(hls + roff0 + boff);
      bf16x8 a1 = *(const bf16x8*)(hls + roff1 + boff);
      acc0 = __builtin_amdgcn_mfma_f32_16x16x32_bf16(a0, bq[kc], acc0, 0, 0, 0);
      acc1 = __builtin_amdgcn_mfma_f32_16x16x32_bf16(a1, bq[kc], acc1, 0, 0, 0);
    }

    // ---- acc -> zbuf (C/D layout: col = l&15, row = (l>>4)*4 + p) ----
    {
      int colz  = (w << 4) + (l & 15);
      int rbase = ((l >> 4) & 3) * 4;
      #pragma unroll
      for (int p = 0; p < 4; ++p) {
        zbuf[(rbase + p) * 128 + colz]        = acc0[p];
        zbuf[(rbase + p + 16) * 128 + colz]   = acc1[p];
      }
    }
    __syncthreads();

    // ---- gates + c update (f32), write h' (bf16) to global ----
    #pragma unroll
    for (int e = 0; e < 2; ++e) {
      int idx = tid + e * THREADS;
      int r = idx >> 5, hc = idx & 31;
      float xv = xbuf[r];
      float zg = zbuf[r * 128 +       hc] + xv * wxb[      hc] + bbl[      hc];
      float zi = zbuf[r * 128 +  32 + hc] + xv * wxb[ 32 + hc] + bbl[ 32 + hc];
      float zf = zbuf[r * 128 +  64 + hc] + xv * wxb[ 64 + hc] + bbl[ 64 + hc];
      float zo = zbuf[r * 128 +  96 + hc] + xv * wxb[ 96 + hc] + bbl[ 96 + hc];
      float gg = tanhf_(zg);
      float ii = sigmf_(zi);
      float ff = sigmf_(zf);
      float oo = sigmf_(zo);
      float cold = e ? creg1 : creg0;
      float cnew = gg * ii + cold * ff;
      if (e) creg1 = cnew; else creg0 = cnew;
      float hv = tanhf_(cnew) * oo;
      hbuf[(r0 + r) * Hd + hc0 + hc] = f2bf(hv);
    }

    // ---- group barrier (agent scope: cross-XCD release/acquire) ----
    __syncthreads();   // drain all waves' h stores (vmcnt(0) before s_barrier)
    if (tid == 0) {
      __hip_atomic_store(&myflags[j], (unsigned)(t + 1),
                         __ATOMIC_RELEASE, __HIP_MEMORY_SCOPE_AGENT);
    }
    if (tid < 64) {
      unsigned* f = &myflags[tid & 31];
      while (__hip_atomic_load(f, __ATOMIC_ACQUIRE, __HIP_MEMORY_SCOPE_AGENT)
             < (unsigned)(t + 1)) {
        __builtin_amdgcn_s_sleep(1);
      }
    }
    __syncthreads();

    // ---- stage h_{t+1} (own 32 rows, all 1024 cols) global -> LDS swizzled ----
    #pragma unroll
    for (int i = 0; i < 8; ++i) {
      int m = tid + i * THREADS;         // 4096 chunks of 16B
      int r = m >> 7, k16 = m & 127;
      u32x4 v = *(const u32x4*)(hbuf + (r0 + r) * Hd + k16 * 8);
      *(u32x4*)(hls + r * 2048 + ((k16 * 16) ^ ((r & 7) << 4))) = v;
    }
    __syncthreads();
  }

  // ---- projection + softmax: one block per group ----
  if (j == 0) {
    if (tid < 320) {
      int r = tid / 10;
      int cls = tid - r * 10;
      float acc = bp[cls];
      for (int k16 = 0; k16 < 128; ++k16) {
        const unsigned short* hp =
            (const unsigned short*)(hls + r * 2048 + ((k16 * 16) ^ ((r & 7) << 4)));
        #pragma unroll
        for (int e = 0; e < 8; ++e) {
          acc += bf2f(hp[e]) * wph[(k16 * 8 + e) * Cc + cls];
        }
      }
      zbuf[r * 16 + cls] = acc;
    }
    __syncthreads();
    if (tid < 32) {
      int r = tid;
      float m = -1e30f;
      #pragma unroll
      for (int cc = 0; cc < Cc; ++cc) m = fmaxf(m, zbuf[r * 16 + cc]);
      float s = 0.f;
      float ev[Cc];
      #pragma unroll
      for (int cc = 0; cc < Cc; ++cc) { ev[cc] = __expf(zbuf[r * 16 + cc] - m); s += ev[cc]; }
      float inv = 1.0f / s;
      #pragma unroll
      for (int cc = 0; cc < Cc; ++cc) out[(r0 + r) * Cc + cc] = ev[cc] * inv;
    }
  }
}

extern "C" void kernel_launch(void* const* d_in, const int* in_sizes, int n_in,
                              void* d_out, int out_size, void* d_ws, size_t ws_size,
                              hipStream_t stream) {
  const float* x   = (const float*)d_in[0];
  const float* wgx = (const float*)d_in[1];
  const float* wgh = (const float*)d_in[2];
  const float* bg  = (const float*)d_in[3];
  const float* wix = (const float*)d_in[4];
  const float* wih = (const float*)d_in[5];
  const float* bi  = (const float*)d_in[6];
  const float* wfx = (const float*)d_in[7];
  const float* wfh = (const float*)d_in[8];
  const float* bfp = (const float*)d_in[9];
  const float* wox = (const float*)d_in[10];
  const float* woh = (const float*)d_in[11];
  const float* bo  = (const float*)d_in[12];
  const float* wph = (const float*)d_in[13];
  const float* bp  = (const float*)d_in[14];
  float* out = (float*)d_out;

  unsigned short* hbuf = (unsigned short*)d_ws;                        // 512KB
  unsigned* flags = (unsigned*)((char*)d_ws + (size_t)Bsz * Hd * 2);   // 1KB

  hipMemsetAsync(flags, 0, 256 * sizeof(unsigned), stream);

  size_t shmem = 65536 + 16384 + (32 + 128 + 128) * sizeof(float);
  hipFuncSetAttribute((const void*)lstm_kernel,
                      hipFuncAttributeMaxDynamicSharedMemorySize, (int)shmem);

  void* args[] = {
    (void*)&x,   (void*)&wgx, (void*)&wgh, (void*)&bg,
    (void*)&wix, (void*)&wih, (void*)&bi,
    (void*)&wfx, (void*)&wfh, (void*)&bfp,
    (void*)&wox, (void*)&woh, (void*)&bo,
    (void*)&wph, (void*)&bp,
    (void*)&out, (void*)&hbuf, (void*)&flags
  };
  hipLaunchCooperativeKernel((const void*)lstm_kernel, dim3(256), dim3(512),
                             args, (unsigned)shmem, stream);
}